// Round 8
// baseline (510.316 us; speedup 1.0000x reference)
//
#include <hip/hip_runtime.h>
#include <hip/hip_cooperative_groups.h>
#include <cstdint>
#include <cstddef>

namespace cg = cooperative_groups;

typedef __attribute__((ext_vector_type(8))) __bf16 bf16x8;
typedef __attribute__((ext_vector_type(4))) float f32x4;

union bf8pack { unsigned short u[8]; bf16x8 v; uint4 q; };

static __device__ __forceinline__ unsigned short f2b(float f) {
    union { float f; unsigned int u; } v; v.f = f;
    unsigned int u = v.u;
    unsigned int r = (u + 0x7fffu + ((u >> 16) & 1u)) >> 16;  // RNE
    return (unsigned short)r;
}

// ---------------------------------------------------------------------------
// Phase device functions (shared by cooperative kernel and fallback wrappers)
// ---------------------------------------------------------------------------

// GEMM tile (64x64/wave, 2x2 waves = 128x128/block), bf16 MFMA 16x16x32.
// A: m=lane&15,k=quad*8+j; B: n=lane&15,k=quad*8+j; C/D: col=lane&15,row=quad*4+r
template<int K, int ACT>
static __device__ __forceinline__ void gemm_tile(
    const unsigned short* __restrict__ A, int strideA,
    const unsigned short* __restrict__ W, const float* __restrict__ bias,
    unsigned short* __restrict__ C, int Ncols, int bm, int bnt, int tid)
{
    const int w = tid >> 6, wm = w & 1, wn = w >> 1;
    const int l = tid & 63, lr = l & 15, quad = l >> 4;
    const int m0 = bm * 128 + wm * 64;
    const int n0 = bnt * 128 + wn * 64;

    f32x4 acc[4][4];
#pragma unroll
    for (int i = 0; i < 4; i++)
#pragma unroll
        for (int j = 0; j < 4; j++) acc[i][j] = (f32x4){0.f, 0.f, 0.f, 0.f};

    const unsigned short* Ap = A + (size_t)(m0 + lr) * strideA + quad * 8;
    const unsigned short* Bp = W + (size_t)(n0 + lr) * K + quad * 8;

#pragma unroll
    for (int ks = 0; ks < K / 32; ks++) {
        bf16x8 af[4], bfr[4];
#pragma unroll
        for (int i = 0; i < 4; i++)
            af[i] = *(const bf16x8*)(Ap + (size_t)i * 16 * strideA + ks * 32);
#pragma unroll
        for (int i = 0; i < 4; i++)
            bfr[i] = *(const bf16x8*)(Bp + (size_t)i * 16 * K + ks * 32);
#pragma unroll
        for (int mi = 0; mi < 4; mi++)
#pragma unroll
            for (int ni = 0; ni < 4; ni++)
                acc[mi][ni] = __builtin_amdgcn_mfma_f32_16x16x32_bf16(
                    af[mi], bfr[ni], acc[mi][ni], 0, 0, 0);
    }

#pragma unroll
    for (int ni = 0; ni < 4; ni++) {
        const int col = n0 + ni * 16 + lr;
        const float bv = bias[col];
#pragma unroll
        for (int mi = 0; mi < 4; mi++) {
#pragma unroll
            for (int r = 0; r < 4; r++) {
                const int row = m0 + mi * 16 + quad * 4 + r;
                float v = acc[mi][ni][r] + bv;
                if (ACT == 1) v = v > 0.f ? v : 0.f;
                if (ACT == 2) v = v > 0.f ? v : 0.01f * v;
                C[(size_t)row * Ncols + col] = f2b(v);
            }
        }
    }
}

// K1 tile: y[128,128] = relu(x(fp32)@Wp(fp32)^T + bp); writes xb=bf16(x) into
// bufX[:,0:128] (wn==0 waves). In-register fp32->bf16.
static __device__ __forceinline__ void k1_tile(
    int bm, const float* __restrict__ x, const float* __restrict__ Wp,
    const float* __restrict__ bp, unsigned short* __restrict__ bufX,
    unsigned short* __restrict__ yb, int tid)
{
    const int w = tid >> 6, wm = w & 1, wn = w >> 1;
    const int l = tid & 63, lr = l & 15, quad = l >> 4;
    const int m0 = bm * 128 + wm * 64;
    const int n0 = wn * 64;

    f32x4 acc[4][4];
#pragma unroll
    for (int i = 0; i < 4; i++)
#pragma unroll
        for (int j = 0; j < 4; j++) acc[i][j] = (f32x4){0.f, 0.f, 0.f, 0.f};

    const float* Ap = x + (size_t)(m0 + lr) * 128 + quad * 8;
    const float* Bp = Wp + (size_t)(n0 + lr) * 128 + quad * 8;

#pragma unroll
    for (int ks = 0; ks < 4; ks++) {
        bf16x8 af[4], bfr[4];
#pragma unroll
        for (int i = 0; i < 4; i++) {
            const float* p = Ap + (size_t)i * 16 * 128 + ks * 32;
            float4 f0 = *(const float4*)p, f1 = *(const float4*)(p + 4);
            bf8pack pk;
            pk.u[0] = f2b(f0.x); pk.u[1] = f2b(f0.y);
            pk.u[2] = f2b(f0.z); pk.u[3] = f2b(f0.w);
            pk.u[4] = f2b(f1.x); pk.u[5] = f2b(f1.y);
            pk.u[6] = f2b(f1.z); pk.u[7] = f2b(f1.w);
            af[i] = pk.v;
            if (wn == 0)
                *(uint4*)(bufX + (size_t)(m0 + lr + i * 16) * 256 + ks * 32 + quad * 8) = pk.q;
        }
#pragma unroll
        for (int i = 0; i < 4; i++) {
            const float* p = Bp + (size_t)i * 16 * 128 + ks * 32;
            float4 f0 = *(const float4*)p, f1 = *(const float4*)(p + 4);
            bf8pack pk;
            pk.u[0] = f2b(f0.x); pk.u[1] = f2b(f0.y);
            pk.u[2] = f2b(f0.z); pk.u[3] = f2b(f0.w);
            pk.u[4] = f2b(f1.x); pk.u[5] = f2b(f1.y);
            pk.u[6] = f2b(f1.z); pk.u[7] = f2b(f1.w);
            bfr[i] = pk.v;
        }
#pragma unroll
        for (int mi = 0; mi < 4; mi++)
#pragma unroll
            for (int ni = 0; ni < 4; ni++)
                acc[mi][ni] = __builtin_amdgcn_mfma_f32_16x16x32_bf16(
                    af[mi], bfr[ni], acc[mi][ni], 0, 0, 0);
    }

#pragma unroll
    for (int ni = 0; ni < 4; ni++) {
        const int col = n0 + ni * 16 + lr;
        const float bv = bp[col];
#pragma unroll
        for (int mi = 0; mi < 4; mi++) {
#pragma unroll
            for (int r = 0; r < 4; r++) {
                const int row = m0 + mi * 16 + quad * 4 + r;
                float v = acc[mi][ni][r] + bv;
                v = v > 0.f ? v : 0.f;
                yb[(size_t)row * 128 + col] = f2b(v);
            }
        }
    }
}

// count chunk c (8192 edges): LDS histogram of 2048 buckets -> global add.
static __device__ __forceinline__ void count_chunk(
    int c, const int* __restrict__ dst, int* __restrict__ bcnt,
    int* smem, int tid)
{
    int* h = smem;
    for (int i = tid; i < 2048; i += 256) h[i] = 0;
    __syncthreads();
    const int base = c * 8192;
#pragma unroll
    for (int i = 0; i < 32; i++)
        atomicAdd(&h[((unsigned)dst[base + i * 256 + tid]) >> 5], 1);
    __syncthreads();
    for (int i = tid; i < 2048; i += 256)
        if (h[i]) atomicAdd(&bcnt[i], h[i]);
    __syncthreads();
}

// weight convert chunk c (0..4): Wcat / W1_b / W2_b
static __device__ __forceinline__ void convw_chunk(
    int c, const float* __restrict__ Ws, const float* __restrict__ Wn,
    const float* __restrict__ W1, const float* __restrict__ W2,
    unsigned short* __restrict__ Wcat, unsigned short* __restrict__ W1_b,
    unsigned short* __restrict__ W2_b, int tid)
{
    int i = c * 16384 + tid;
    for (int k = 0; k < 64; k++, i += 256) {
        if (i < 32768) {
            int o = i >> 8, kk = i & 255;
            Wcat[i] = f2b(kk < 128 ? Ws[o * 128 + kk] : Wn[o * 128 + (kk - 128)]);
        } else if (i < 65536) {
            W1_b[i - 32768] = f2b(W1[i - 32768]);
        } else if (i < 69632) {
            W2_b[i - 65536] = f2b(W2[i - 65536]);
        }
    }
}

// scan of 2048 bucket counts by one 256-thread block (8 counts/thread).
static __device__ __forceinline__ void scan2048(
    const int* __restrict__ bcnt, int* __restrict__ boff,
    int* __restrict__ bcur, int* smem, int tid)
{
    int loc[8]; const int base = tid * 8; int s = 0;
#pragma unroll
    for (int j = 0; j < 8; j++) { loc[j] = bcnt[base + j]; s += loc[j]; }
    smem[tid] = s;
    __syncthreads();
    for (int d = 1; d < 256; d <<= 1) {
        int add = (tid >= d) ? smem[tid - d] : 0;
        __syncthreads();
        smem[tid] += add;
        __syncthreads();
    }
    int run = tid ? smem[tid - 1] : 0;
#pragma unroll
    for (int j = 0; j < 8; j++) { boff[base + j] = run; bcur[base + j] = run; run += loc[j]; }
    if (tid == 255) boff[2048] = run;
    __syncthreads();
}

// scatter chunk c (4096 edges): two-level chunk reservation, packed pairs.
static __device__ __forceinline__ void scatter_chunk(
    int c, const int* __restrict__ src, const int* __restrict__ dst,
    int* __restrict__ bcur, unsigned int* __restrict__ pairs,
    int* smem, int tid)
{
    int* h = smem; int* base_l = smem + 2048; int* cntl = smem + 4096;
    for (int i = tid; i < 2048; i += 256) { h[i] = 0; cntl[i] = 0; }
    __syncthreads();
    const int base = c * 4096;
    int d_r[16], s_r[16];
#pragma unroll
    for (int i = 0; i < 16; i++) {
        int e = base + i * 256 + tid;
        d_r[i] = dst[e]; s_r[i] = src[e];
        atomicAdd(&h[((unsigned)d_r[i]) >> 5], 1);
    }
    __syncthreads();
    for (int i = tid; i < 2048; i += 256)
        base_l[i] = h[i] ? atomicAdd(&bcur[i], h[i]) : 0;
    __syncthreads();
#pragma unroll
    for (int i = 0; i < 16; i++) {
        int bk = ((unsigned)d_r[i]) >> 5;
        int pos = base_l[bk] + atomicAdd(&cntl[bk], 1);
        pairs[pos] = ((unsigned)s_r[i] << 5) | ((unsigned)d_r[i] & 31u);
    }
    __syncthreads();
}

// pool one bucket (32 dst nodes): counting-sort by dst into LDS, then each
// wave owns 8 nodes; 8-deep clamped gather batches, register fmax.
static __device__ __forceinline__ void pool_bucket(
    int bk, const unsigned int* __restrict__ yu, const int* __restrict__ boff,
    const unsigned int* __restrict__ pairs, unsigned short* __restrict__ bufX,
    int* smem, int tid)
{
    int* bin = smem; int* offl = smem + 32; int* cnt2 = smem + 64;
    unsigned short* ldsSrc = (unsigned short*)(smem + 96);
    if (tid < 32) { bin[tid] = 0; cnt2[tid] = 0; }
    __syncthreads();
    const int beg = boff[bk];
    const int nb = boff[bk + 1] - beg;

    for (int i = tid; i < nb; i += 256)
        atomicAdd(&bin[pairs[beg + i] & 31u], 1);
    __syncthreads();
    if (tid == 0) {
        int run = 0;
        for (int i = 0; i < 32; i++) { offl[i] = run; run += bin[i]; }
    }
    __syncthreads();
    for (int i = tid; i < nb; i += 256) {
        unsigned int p = pairs[beg + i];
        int d = p & 31u;
        ldsSrc[offl[d] + atomicAdd(&cnt2[d], 1)] = (unsigned short)(p >> 5);
    }
    __syncthreads();

    const int w = tid >> 6, lane = tid & 63;
    for (int ni = 0; ni < 8; ni++) {
        const int n = w * 8 + ni;
        const int e0 = offl[n], cnt = bin[n];
        float ax = 0.f, ay = 0.f;
        for (int e = 0; e < cnt; e += 8) {
            int s[8]; unsigned int v[8];
#pragma unroll
            for (int j = 0; j < 8; j++) {
                int idx = e + j; idx = idx < cnt ? idx : cnt - 1;   // clamp: dup last
                s[j] = ldsSrc[e0 + idx];
            }
#pragma unroll
            for (int j = 0; j < 8; j++) v[j] = yu[(size_t)s[j] * 64 + lane];
#pragma unroll
            for (int j = 0; j < 8; j++) {
                ax = fmaxf(ax, __uint_as_float(v[j] << 16));
                ay = fmaxf(ay, __uint_as_float(v[j] & 0xffff0000u));
            }
        }
        unsigned int packed = (__float_as_uint(ax) >> 16) | (__float_as_uint(ay) & 0xffff0000u);
        ((unsigned int*)bufX)[(size_t)(bk * 32 + n) * 128 + 64 + lane] = packed;
    }
    __syncthreads();
}

// head job j: 64 rows -> out = sigmoid(H @ W2^T + b2)
static __device__ __forceinline__ void head_job(
    int j, const unsigned short* __restrict__ H,
    const unsigned short* __restrict__ W2b, const float* __restrict__ b2,
    float* __restrict__ out, int tid)
{
    const int w = tid >> 6, l = tid & 63, lr = l & 15, quad = l >> 4;
    const int m0 = j * 64 + w * 16;
    f32x4 acc = (f32x4){0.f, 0.f, 0.f, 0.f};
#pragma unroll
    for (int ks = 0; ks < 8; ks++) {
        bf16x8 a = *(const bf16x8*)(H + (size_t)(m0 + lr) * 256 + ks * 32 + quad * 8);
        bf16x8 bb = *(const bf16x8*)(W2b + (size_t)lr * 256 + ks * 32 + quad * 8);
        acc = __builtin_amdgcn_mfma_f32_16x16x32_bf16(a, bb, acc, 0, 0, 0);
    }
    const float bv = b2[lr];
#pragma unroll
    for (int r = 0; r < 4; r++) {
        const int row = m0 + quad * 4 + r;
        float v = acc[r] + bv;
        out[(size_t)row * 16 + lr] = 1.f / (1.f + __expf(-v));
    }
}

// ---------------------------------------------------------------------------
// Cooperative mega-kernel — grid-size agnostic (persistent blocks).
// ---------------------------------------------------------------------------
__global__ __launch_bounds__(256, 2) void fused_gnn(
    const float* __restrict__ x,  const float* __restrict__ Wp,
    const float* __restrict__ bp, const float* __restrict__ Ws,
    const float* __restrict__ Wn, const float* __restrict__ bn,
    const float* __restrict__ W1, const float* __restrict__ b1,
    const float* __restrict__ W2, const float* __restrict__ b2,
    const int* __restrict__ src,  const int* __restrict__ dst,
    float* __restrict__ out,
    unsigned short* bufX, unsigned short* y, unsigned short* hbuf,
    unsigned short* h2, unsigned short* Wcat, unsigned short* W1_b,
    unsigned short* W2_b, int* bcnt, int* cursor, int* boff, int* bcur,
    unsigned int* pairs)
{
    __shared__ int smem[6144];   // 24 KB, reused per phase
    __shared__ int sh_t;
    cg::grid_group grid = cg::this_grid();
    const int b = blockIdx.x;
    const int G = gridDim.x;
    const int tid = threadIdx.x;

    // Phase A: bucket count + weight convert + K1 (work-stealing)
    for (int c = b; c < 128; c += G) count_chunk(c, dst, bcnt, smem, tid);
    for (int c = b; c < 5; c += G)
        convw_chunk(c, Ws, Wn, W1, W2, Wcat, W1_b, W2_b, tid);
    for (;;) {
        if (tid == 0) sh_t = atomicAdd(cursor, 1);
        __syncthreads();
        const int t = sh_t;
        __syncthreads();
        if (t >= 512) break;
        k1_tile(t, x, Wp, bp, bufX, y, tid);
    }
    grid.sync();

    // Phase B: scan
    if (b == 0) scan2048(bcnt, boff, bcur, smem, tid);
    grid.sync();

    // Phase C: scatter
    for (int c = b; c < 256; c += G)
        scatter_chunk(c, src, dst, bcur, pairs, smem, tid);
    grid.sync();

    // Phase D: pool
    for (int c = b; c < 2048; c += G)
        pool_bucket(c, (const unsigned int*)y, boff, pairs, bufX, smem, tid);
    grid.sync();

    // Phase F: K4  h = leaky(concat(xb,pooled) @ Wcat^T + bn)
    for (int c = b; c < 512; c += G)
        gemm_tile<256, 2>(bufX, 256, Wcat, bn, hbuf, 128, c, 0, tid);
    grid.sync();

    // Phase G: K5  h2 = leaky(h @ W1^T + b1)
    for (int c = b; c < 1024; c += G)
        gemm_tile<128, 2>(hbuf, 128, W1_b, b1, h2, 256, c >> 1, c & 1, tid);
    grid.sync();

    // Phase H: head
    for (int c = b; c < 1024; c += G)
        head_job(c, h2, W2_b, b2, out, tid);
}

// ---------------------------------------------------------------------------
// Fallback wrappers (regular launches) — same device functions.
// ---------------------------------------------------------------------------
__global__ __launch_bounds__(256) void fb_count_conv(
    const int* dst, int* bcnt, const float* Ws, const float* Wn,
    const float* W1, const float* W2, unsigned short* Wcat,
    unsigned short* W1_b, unsigned short* W2_b)
{
    __shared__ int smem[2048];
    if ((int)blockIdx.x < 128)
        count_chunk(blockIdx.x, dst, bcnt, smem, threadIdx.x);
    else
        convw_chunk(blockIdx.x - 128, Ws, Wn, W1, W2, Wcat, W1_b, W2_b, threadIdx.x);
}

__global__ __launch_bounds__(256) void fb_scan(
    const int* bcnt, int* boff, int* bcur)
{
    __shared__ int smem[256];
    scan2048(bcnt, boff, bcur, smem, threadIdx.x);
}

__global__ __launch_bounds__(256) void fb_scatter(
    const int* src, const int* dst, int* bcur, unsigned int* pairs)
{
    __shared__ int smem[6144];
    scatter_chunk(blockIdx.x, src, dst, bcur, pairs, smem, threadIdx.x);
}

__global__ __launch_bounds__(256) void fb_k1(
    const float* x, const float* Wp, const float* bp,
    unsigned short* bufX, unsigned short* y)
{
    k1_tile(blockIdx.x, x, Wp, bp, bufX, y, threadIdx.x);
}

__global__ __launch_bounds__(256) void fb_pool(
    const unsigned int* yu, const int* boff, const unsigned int* pairs,
    unsigned short* bufX)
{
    __shared__ int smem[2144];   // 96 + 4096 shorts
    pool_bucket(blockIdx.x, yu, boff, pairs, bufX, smem, threadIdx.x);
}

__global__ __launch_bounds__(256) void fb_k4(
    const unsigned short* bufX, const unsigned short* Wcat, const float* bn,
    unsigned short* hbuf)
{
    gemm_tile<256, 2>(bufX, 256, Wcat, bn, hbuf, 128, blockIdx.x, 0, threadIdx.x);
}

__global__ __launch_bounds__(256) void fb_k5(
    const unsigned short* hbuf, const unsigned short* W1_b, const float* b1,
    unsigned short* h2)
{
    gemm_tile<128, 2>(hbuf, 128, W1_b, b1, h2, 256,
                      (int)blockIdx.x >> 1, (int)blockIdx.x & 1, threadIdx.x);
}

__global__ __launch_bounds__(256) void fb_head(
    const unsigned short* h2, const unsigned short* W2_b, const float* b2,
    float* out)
{
    head_job(blockIdx.x, h2, W2_b, b2, out, threadIdx.x);
}

// ---------------------------------------------------------------------------
extern "C" void kernel_launch(void* const* d_in, const int* in_sizes, int n_in,
                              void* d_out, int out_size, void* d_ws, size_t ws_size,
                              hipStream_t stream)
{
    const float* x  = (const float*)d_in[0];
    const float* Wp = (const float*)d_in[1];
    const float* bp = (const float*)d_in[2];
    const float* Ws = (const float*)d_in[3];
    const float* Wn = (const float*)d_in[4];
    const float* bn = (const float*)d_in[5];
    const float* W1 = (const float*)d_in[6];
    const float* b1 = (const float*)d_in[7];
    const float* W2 = (const float*)d_in[8];
    const float* b2 = (const float*)d_in[9];
    const int* src  = (const int*)d_in[10];
    const int* dst  = (const int*)d_in[11];
    float* out = (float*)d_out;

    // ws layout:
    //   [ 0,32M)  bufX : [N,256] bf16 — cols 0:128 = xb, cols 128:256 = pooled
    //   [32M,48M) y    : [N,128] bf16
    //   [48M,64M) hbuf : [N,128] bf16
    //   [64M,96M) h2   : [N,256] bf16
    //   [96M,..)  bf16 weights, bucket ints, pairs (4MB)
    unsigned short* bufX = (unsigned short*)d_ws;
    unsigned short* y    = (unsigned short*)((char*)d_ws + (size_t)32 * 1024 * 1024);
    unsigned short* hbuf = (unsigned short*)((char*)d_ws + (size_t)48 * 1024 * 1024);
    unsigned short* h2   = (unsigned short*)((char*)d_ws + (size_t)64 * 1024 * 1024);

    unsigned short* Wcat = (unsigned short*)((char*)d_ws + (size_t)96 * 1024 * 1024);
    unsigned short* W1_b = Wcat + 32768;     // 256 x 128
    unsigned short* W2_b = W1_b + 32768;     // 16 x 256
    int* bcnt   = (int*)(W2_b + 4096);       // 2048 (zeroed)
    int* cursor = bcnt + 2048;               // 16   (zeroed, same memset)
    int* boff   = cursor + 16;               // 2049
    int* bcur   = boff + 2064;               // 2048
    unsigned int* pairs = (unsigned int*)(bcur + 2048);   // E

    hipMemsetAsync(bcnt, 0, (2048 + 16) * sizeof(int), stream);

    // Try cooperative single-kernel; fall back to multi-dispatch chain.
    bool ok = false;
    int maxBlk = 0;
    hipError_t qe = hipOccupancyMaxActiveBlocksPerMultiprocessor(
        &maxBlk, (const void*)fused_gnn, 256, 0);
    if (qe == hipSuccess && maxBlk > 0) {
        int gridN = maxBlk * 256;            // 256 CUs on MI355X
        if (gridN > 512) gridN = 512;
        void* args[] = {
            (void*)&x, (void*)&Wp, (void*)&bp, (void*)&Ws, (void*)&Wn, (void*)&bn,
            (void*)&W1, (void*)&b1, (void*)&W2, (void*)&b2, (void*)&src, (void*)&dst,
            (void*)&out, (void*)&bufX, (void*)&y, (void*)&hbuf, (void*)&h2,
            (void*)&Wcat, (void*)&W1_b, (void*)&W2_b, (void*)&bcnt, (void*)&cursor,
            (void*)&boff, (void*)&bcur, (void*)&pairs
        };
        hipError_t le = hipLaunchCooperativeKernel((void*)fused_gnn, dim3(gridN),
                                                   dim3(256), args, 0, stream);
        ok = (le == hipSuccess);
    }
    if (!ok) {
        (void)hipGetLastError();   // clear failed-launch state
        dim3 blk(256);
        fb_count_conv<<<133, blk, 0, stream>>>(dst, bcnt, Ws, Wn, W1, W2,
                                               Wcat, W1_b, W2_b);
        fb_k1<<<512, blk, 0, stream>>>(x, Wp, bp, bufX, y);
        fb_scan<<<1, blk, 0, stream>>>(bcnt, boff, bcur);
        fb_scatter<<<256, blk, 0, stream>>>(src, dst, bcur, pairs);
        fb_pool<<<2048, blk, 0, stream>>>((const unsigned int*)y, boff, pairs, bufX);
        fb_k4<<<512, blk, 0, stream>>>(bufX, Wcat, bn, hbuf);
        fb_k5<<<1024, blk, 0, stream>>>(hbuf, W1_b, b1, h2);
        fb_head<<<1024, blk, 0, stream>>>(h2, W2_b, b2, out);
    }
    (void)in_sizes; (void)n_in; (void)out_size; (void)ws_size;
}

// Round 10
// 227.233 us; speedup vs baseline: 2.2458x; 2.2458x over previous
//
#include <hip/hip_runtime.h>
#include <cstdint>
#include <cstddef>

typedef __attribute__((ext_vector_type(8))) __bf16 bf16x8;
typedef __attribute__((ext_vector_type(4))) float f32x4;

union bf8pack { unsigned short u[8]; bf16x8 v; uint4 q; };

static __device__ __forceinline__ unsigned short f2b(float f) {
    union { float f; unsigned int u; } v; v.f = f;
    unsigned int u = v.u;
    unsigned int r = (u + 0x7fffu + ((u >> 16) & 1u)) >> 16;  // RNE
    return (unsigned short)r;
}

// ---------------------------------------------------------------------------
// MFMA GEMM (R6-proven): C[M,Ncols](bf16) = act(A[M,K] @ W[Ncols,K]^T + bias)
// Block 256 thr = 4 waves (2x2), wave does 64x64 via 4x4 tiles of 16x16x32.
// A: m=lane&15,k=quad*8+j; B: n=lane&15,k=quad*8+j; C/D: col=lane&15,row=quad*4+r
// ---------------------------------------------------------------------------
template<int K, int ACT>
__global__ __launch_bounds__(256) void mfma_gemm(
    const unsigned short* __restrict__ A, int strideA,
    const unsigned short* __restrict__ W,
    const float* __restrict__ bias,
    unsigned short* __restrict__ C, int Ncols)
{
    const int nt = Ncols >> 7;
    const int bm = (int)blockIdx.x / nt, bn = (int)blockIdx.x % nt;
    const int w  = threadIdx.x >> 6;
    const int wm = w & 1, wn = w >> 1;
    const int l  = threadIdx.x & 63;
    const int lr = l & 15, quad = l >> 4;
    const int m0 = bm * 128 + wm * 64;
    const int n0 = bn * 128 + wn * 64;

    f32x4 acc[4][4];
#pragma unroll
    for (int i = 0; i < 4; i++)
#pragma unroll
        for (int j = 0; j < 4; j++) acc[i][j] = (f32x4){0.f, 0.f, 0.f, 0.f};

    const unsigned short* Ap = A + (size_t)(m0 + lr) * strideA + quad * 8;
    const unsigned short* Bp = W + (size_t)(n0 + lr) * K + quad * 8;

    for (int ks = 0; ks < K / 32; ks++) {
        bf16x8 af[4], bf[4];
#pragma unroll
        for (int i = 0; i < 4; i++)
            af[i] = *(const bf16x8*)(Ap + (size_t)i * 16 * strideA + ks * 32);
#pragma unroll
        for (int i = 0; i < 4; i++)
            bf[i] = *(const bf16x8*)(Bp + (size_t)i * 16 * K + ks * 32);
#pragma unroll
        for (int mi = 0; mi < 4; mi++)
#pragma unroll
            for (int ni = 0; ni < 4; ni++)
                acc[mi][ni] = __builtin_amdgcn_mfma_f32_16x16x32_bf16(
                    af[mi], bf[ni], acc[mi][ni], 0, 0, 0);
    }

#pragma unroll
    for (int ni = 0; ni < 4; ni++) {
        const int col = n0 + ni * 16 + lr;
        const float bv = bias[col];
#pragma unroll
        for (int mi = 0; mi < 4; mi++) {
#pragma unroll
            for (int r = 0; r < 4; r++) {
                const int row = m0 + mi * 16 + quad * 4 + r;
                float v = acc[mi][ni][r] + bv;
                if (ACT == 1) v = v > 0.f ? v : 0.f;
                if (ACT == 2) v = v > 0.f ? v : 0.01f * v;
                C[(size_t)row * Ncols + col] = f2b(v);
            }
        }
    }
}

// ---------------------------------------------------------------------------
// K1 fused (R6-proven): y = relu(x(fp32) @ Wp_b^T + bp), and writes
// xb=bf16(x) into bufX[:,0:128] (wn==0 waves).
// ---------------------------------------------------------------------------
__global__ __launch_bounds__(256) void k1_fused(
    const float* __restrict__ x, const unsigned short* __restrict__ Wp_b,
    const float* __restrict__ bias, unsigned short* __restrict__ bufX,
    unsigned short* __restrict__ y)
{
    const int bm = blockIdx.x;
    const int w  = threadIdx.x >> 6;
    const int wm = w & 1, wn = w >> 1;
    const int l  = threadIdx.x & 63;
    const int lr = l & 15, quad = l >> 4;
    const int m0 = bm * 128 + wm * 64;
    const int n0 = wn * 64;

    f32x4 acc[4][4];
#pragma unroll
    for (int i = 0; i < 4; i++)
#pragma unroll
        for (int j = 0; j < 4; j++) acc[i][j] = (f32x4){0.f, 0.f, 0.f, 0.f};

    const float* Ap = x + (size_t)(m0 + lr) * 128 + quad * 8;
    const unsigned short* Bp = Wp_b + (size_t)(n0 + lr) * 128 + quad * 8;

#pragma unroll
    for (int ks = 0; ks < 4; ks++) {
        bf16x8 af[4], bf[4];
#pragma unroll
        for (int i = 0; i < 4; i++) {
            const float* p = Ap + (size_t)i * 16 * 128 + ks * 32;
            float4 f0 = *(const float4*)p;
            float4 f1 = *(const float4*)(p + 4);
            bf8pack pk;
            pk.u[0] = f2b(f0.x); pk.u[1] = f2b(f0.y);
            pk.u[2] = f2b(f0.z); pk.u[3] = f2b(f0.w);
            pk.u[4] = f2b(f1.x); pk.u[5] = f2b(f1.y);
            pk.u[6] = f2b(f1.z); pk.u[7] = f2b(f1.w);
            af[i] = pk.v;
            if (wn == 0)   // cols 0:128 of bufX = xb
                *(uint4*)(bufX + (size_t)(m0 + lr + i * 16) * 256 + ks * 32 + quad * 8) = pk.q;
        }
#pragma unroll
        for (int i = 0; i < 4; i++)
            bf[i] = *(const bf16x8*)(Bp + (size_t)i * 16 * 128 + ks * 32);
#pragma unroll
        for (int mi = 0; mi < 4; mi++)
#pragma unroll
            for (int ni = 0; ni < 4; ni++)
                acc[mi][ni] = __builtin_amdgcn_mfma_f32_16x16x32_bf16(
                    af[mi], bf[ni], acc[mi][ni], 0, 0, 0);
    }

#pragma unroll
    for (int ni = 0; ni < 4; ni++) {
        const int col = n0 + ni * 16 + lr;
        const float bv = bias[col];
#pragma unroll
        for (int mi = 0; mi < 4; mi++) {
#pragma unroll
            for (int r = 0; r < 4; r++) {
                const int row = m0 + mi * 16 + quad * 4 + r;
                float v = acc[mi][ni][r] + bv;
                v = v > 0.f ? v : 0.f;
                y[(size_t)row * 128 + col] = f2b(v);
            }
        }
    }
}

// ---------------------------------------------------------------------------
// k5_head (NEW, deterministic): block = 64 rows. Phase 1: h2[64,256] =
// leaky(h @ W1^T + b1) into LDS (pad 8). Phase 2: out[64,16] =
// sigmoid(h2 @ W2^T + b2), one 16x16 MFMA per wave. h2 never touches HBM.
// ---------------------------------------------------------------------------
__global__ __launch_bounds__(256) void k5_head(
    const unsigned short* __restrict__ hbuf, const unsigned short* __restrict__ W1_b,
    const float* __restrict__ b1, const unsigned short* __restrict__ W2_b,
    const float* __restrict__ b2, float* __restrict__ out)
{
    __shared__ unsigned short H2[64 * 264];
    const int tid = threadIdx.x;
    const int w = tid >> 6, l = tid & 63;
    const int lr = l & 15, quad = l >> 4;
    const int wm = w & 1, wn = w >> 1;     // wm: 32-row half, wn: 128-col half
    const int row0 = blockIdx.x * 64;

    f32x4 acc[2][8];
#pragma unroll
    for (int i = 0; i < 2; i++)
#pragma unroll
        for (int j = 0; j < 8; j++) acc[i][j] = (f32x4){0.f, 0.f, 0.f, 0.f};

    const unsigned short* Ag = hbuf + (size_t)(row0 + wm * 32 + lr) * 128 + quad * 8;
    const unsigned short* Bp = W1_b + (size_t)(wn * 128 + lr) * 128 + quad * 8;

#pragma unroll
    for (int ks = 0; ks < 4; ks++) {
        bf16x8 af[2], bfr[8];
#pragma unroll
        for (int i = 0; i < 2; i++)
            af[i] = *(const bf16x8*)(Ag + (size_t)i * 16 * 128 + ks * 32);
#pragma unroll
        for (int i = 0; i < 8; i++)
            bfr[i] = *(const bf16x8*)(Bp + (size_t)i * 16 * 128 + ks * 32);
#pragma unroll
        for (int mi = 0; mi < 2; mi++)
#pragma unroll
            for (int ni = 0; ni < 8; ni++)
                acc[mi][ni] = __builtin_amdgcn_mfma_f32_16x16x32_bf16(
                    af[mi], bfr[ni], acc[mi][ni], 0, 0, 0);
    }

#pragma unroll
    for (int ni = 0; ni < 8; ni++) {
        const int col = wn * 128 + ni * 16 + lr;
        const float bv = b1[col];
#pragma unroll
        for (int mi = 0; mi < 2; mi++) {
#pragma unroll
            for (int r = 0; r < 4; r++) {
                const int row = wm * 32 + mi * 16 + quad * 4 + r;   // local
                float v = acc[mi][ni][r] + bv;
                v = v > 0.f ? v : 0.01f * v;
                H2[row * 264 + col] = f2b(v);
            }
        }
    }
    __syncthreads();

    // head: wave w -> rows w*16 .. w*16+15
    const int m0 = w * 16;
    f32x4 a2 = (f32x4){0.f, 0.f, 0.f, 0.f};
#pragma unroll
    for (int ks = 0; ks < 8; ks++) {
        bf16x8 a = *(const bf16x8*)&H2[(m0 + lr) * 264 + ks * 32 + quad * 8];
        bf16x8 bb = *(const bf16x8*)(W2_b + (size_t)lr * 256 + ks * 32 + quad * 8);
        a2 = __builtin_amdgcn_mfma_f32_16x16x32_bf16(a, bb, a2, 0, 0, 0);
    }
    const float bv = b2[lr];
#pragma unroll
    for (int r = 0; r < 4; r++) {
        const int row = row0 + m0 + quad * 4 + r;
        float v = a2[r] + bv;
        out[(size_t)row * 16 + lr] = 1.f / (1.f + __expf(-v));
    }
}

// ---------------------------------------------------------------------------
// Bucket pipeline (R6-proven, verbatim): bucket = dst >> 5 (2048 x 32 nodes).
// ---------------------------------------------------------------------------
__global__ __launch_bounds__(256) void count_conv(
    const int* __restrict__ dst, int* __restrict__ bcnt, int E, int ebks,
    const float* __restrict__ Wp, const float* __restrict__ Ws,
    const float* __restrict__ Wn, const float* __restrict__ W1,
    const float* __restrict__ W2,
    unsigned short* __restrict__ Wp_b, unsigned short* __restrict__ Wcat,
    unsigned short* __restrict__ W1_b, unsigned short* __restrict__ W2_b)
{
    if ((int)blockIdx.x >= ebks) {
        int i = ((int)blockIdx.x - ebks) * 256 + threadIdx.x;
        if (i < 16384) {
            Wp_b[i] = f2b(Wp[i]);
        } else if (i < 49152) {
            int j = i - 16384; int o = j >> 8, k = j & 255;
            Wcat[j] = f2b(k < 128 ? Ws[o * 128 + k] : Wn[o * 128 + (k - 128)]);
        } else if (i < 81920) {
            W1_b[i - 49152] = f2b(W1[i - 49152]);
        } else if (i < 86016) {
            W2_b[i - 81920] = f2b(W2[i - 81920]);
        }
        return;
    }
    __shared__ int h[2048];
    for (int i = threadIdx.x; i < 2048; i += 256) h[i] = 0;
    __syncthreads();
    int base = blockIdx.x * 4096;
#pragma unroll
    for (int i = 0; i < 16; i++) {
        int e = base + i * 256 + threadIdx.x;
        if (e < E) atomicAdd(&h[((unsigned)dst[e]) >> 5], 1);
    }
    __syncthreads();
    for (int i = threadIdx.x; i < 2048; i += 256)
        if (h[i]) atomicAdd(&bcnt[i], h[i]);
}

__global__ __launch_bounds__(1024) void bucket_scan(
    const int* __restrict__ bcnt, int* __restrict__ boff, int* __restrict__ bcur)
{
    __shared__ int s[1024];
    int t = threadIdx.x;
    int c0 = bcnt[2 * t], c1 = bcnt[2 * t + 1];
    s[t] = c0 + c1;
    __syncthreads();
    for (int d = 1; d < 1024; d <<= 1) {
        int add = (t >= d) ? s[t - d] : 0;
        __syncthreads();
        s[t] += add;
        __syncthreads();
    }
    int ex = (t == 0) ? 0 : s[t - 1];
    boff[2 * t] = ex;          bcur[2 * t] = ex;
    boff[2 * t + 1] = ex + c0; bcur[2 * t + 1] = ex + c0;
    if (t == 1023) boff[2048] = s[1023];
}

__global__ __launch_bounds__(256) void bucket_scatter(
    const int* __restrict__ src, const int* __restrict__ dst,
    int* __restrict__ bcur, unsigned int* __restrict__ pairs, int E)
{
    __shared__ int h[2048];
    __shared__ int base_l[2048];
    __shared__ int cnt[2048];
    for (int i = threadIdx.x; i < 2048; i += 256) { h[i] = 0; cnt[i] = 0; }
    __syncthreads();
    int base = blockIdx.x * 4096;
    int d_r[16], s_r[16];
#pragma unroll
    for (int i = 0; i < 16; i++) {
        int e = base + i * 256 + threadIdx.x;
        if (e < E) {
            d_r[i] = dst[e]; s_r[i] = src[e];
            atomicAdd(&h[((unsigned)d_r[i]) >> 5], 1);
        } else d_r[i] = -1;
    }
    __syncthreads();
    for (int i = threadIdx.x; i < 2048; i += 256)
        base_l[i] = h[i] ? atomicAdd(&bcur[i], h[i]) : 0;
    __syncthreads();
#pragma unroll
    for (int i = 0; i < 16; i++) {
        if (d_r[i] >= 0) {
            int b = ((unsigned)d_r[i]) >> 5;
            int pos = base_l[b] + atomicAdd(&cnt[b], 1);
            pairs[pos] = ((unsigned)s_r[i] << 5) | ((unsigned)d_r[i] & 31u);
        }
    }
}

// Pool (R6-proven): block = bucket of 32 dst nodes. Counting-sort pairs by
// dst into LDS src-list, each wave owns 8 nodes, 8-deep clamped gather
// batches, register fmax. bf16 store into bufX[:,128:256].
__global__ __launch_bounds__(256) void bucket_pool3(
    const unsigned int* __restrict__ yu, const int* __restrict__ boff,
    const unsigned int* __restrict__ pairs, unsigned short* __restrict__ bufX)
{
    __shared__ unsigned short ldsSrc[2048];
    __shared__ int bin[32], offl[32], cnt2[32];
    const int b = blockIdx.x;
    const int tid = threadIdx.x;
    if (tid < 32) { bin[tid] = 0; cnt2[tid] = 0; }
    __syncthreads();
    const int beg = boff[b];
    const int nb = boff[b + 1] - beg;

    for (int i = tid; i < nb; i += 256)
        atomicAdd(&bin[pairs[beg + i] & 31u], 1);
    __syncthreads();
    if (tid == 0) {
        int run = 0;
        for (int i = 0; i < 32; i++) { offl[i] = run; run += bin[i]; }
    }
    __syncthreads();
    for (int i = tid; i < nb; i += 256) {
        unsigned int p = pairs[beg + i];
        int d = p & 31u;
        int slot = offl[d] + atomicAdd(&cnt2[d], 1);
        ldsSrc[slot] = (unsigned short)(p >> 5);
    }
    __syncthreads();

    const int w = tid >> 6, lane = tid & 63;
    for (int ni = 0; ni < 8; ni++) {
        const int n = w * 8 + ni;
        const int e0 = offl[n], cnt = bin[n];
        float ax = 0.f, ay = 0.f;
        for (int e = 0; e < cnt; e += 8) {
            int s[8]; unsigned int v[8];
#pragma unroll
            for (int j = 0; j < 8; j++) {
                int idx = e + j; idx = idx < cnt ? idx : cnt - 1;   // clamp: dup last
                s[j] = ldsSrc[e0 + idx];
            }
#pragma unroll
            for (int j = 0; j < 8; j++) v[j] = yu[(size_t)s[j] * 64 + lane];
#pragma unroll
            for (int j = 0; j < 8; j++) {
                ax = fmaxf(ax, __uint_as_float(v[j] << 16));
                ay = fmaxf(ay, __uint_as_float(v[j] & 0xffff0000u));
            }
        }
        unsigned int packed = (__float_as_uint(ax) >> 16) | (__float_as_uint(ay) & 0xffff0000u);
        ((unsigned int*)bufX)[(size_t)(b * 32 + n) * 128 + 64 + lane] = packed;
    }
}

// ---------------------------------------------------------------------------
extern "C" void kernel_launch(void* const* d_in, const int* in_sizes, int n_in,
                              void* d_out, int out_size, void* d_ws, size_t ws_size,
                              hipStream_t stream)
{
    const float* x  = (const float*)d_in[0];
    const float* Wp = (const float*)d_in[1];
    const float* bp = (const float*)d_in[2];
    const float* Ws = (const float*)d_in[3];
    const float* Wn = (const float*)d_in[4];
    const float* bn = (const float*)d_in[5];
    const float* W1 = (const float*)d_in[6];
    const float* b1 = (const float*)d_in[7];
    const float* W2 = (const float*)d_in[8];
    const float* b2 = (const float*)d_in[9];
    const int* src  = (const int*)d_in[10];
    const int* dst  = (const int*)d_in[11];
    float* out = (float*)d_out;

    const int N = in_sizes[0] / 128;   // 65536
    const int E = in_sizes[10];        // 1048576

    // ws layout (R6):
    //   [ 0,32M)  bufX : [N,256] bf16 — cols 0:128 = xb, cols 128:256 = pooled
    //   [32M,48M) y    : [N,128] bf16
    //   [48M,64M) hbuf : [N,128] bf16
    //   [96M,..)  bf16 weights, bucket arrays, pairs (4MB)
    unsigned short* bufX = (unsigned short*)d_ws;
    unsigned short* y    = (unsigned short*)((char*)d_ws + (size_t)32 * 1024 * 1024);
    unsigned short* hbuf = (unsigned short*)((char*)d_ws + (size_t)48 * 1024 * 1024);

    unsigned short* Wp_b = (unsigned short*)((char*)d_ws + (size_t)96 * 1024 * 1024);
    unsigned short* Wcat = Wp_b + 16384;     // 128 x 256
    unsigned short* W1_b = Wcat + 32768;     // 256 x 128
    unsigned short* W2_b = W1_b + 32768;     // 16 x 256
    int* bcnt = (int*)(W2_b + 4096);         // 2048
    int* boff = bcnt + 2048;                 // 2049
    int* bcur = boff + 2049 + 3;             // 2048 (16B aligned)
    unsigned int* pairs = (unsigned int*)(bcur + 2048);   // E

    dim3 blk(256);
    const int ebks = (E + 4095) / 4096;      // 256
    const int cbks = (86016 + 255) / 256;    // 336

    // bucket build + weight conversion (fused)
    hipMemsetAsync(bcnt, 0, 2048 * sizeof(int), stream);
    count_conv<<<ebks + cbks, blk, 0, stream>>>(
        dst, bcnt, E, ebks, Wp, Ws, Wn, W1, W2, Wp_b, Wcat, W1_b, W2_b);
    bucket_scan<<<1, 1024, 0, stream>>>(bcnt, boff, bcur);
    bucket_scatter<<<ebks, blk, 0, stream>>>(src, dst, bcur, pairs, E);

    // K1 fused: y = relu(x@Wp^T+bp), bufX[:,0:128] = bf16(x)
    k1_fused<<<N / 128, blk, 0, stream>>>(x, Wp_b, bp, bufX, y);

    // pool: bufX[:,128:256] = segment_max(y[src]) by dst
    bucket_pool3<<<2048, blk, 0, stream>>>((const unsigned int*)y, boff, pairs, bufX);

    // K4: h = leaky(concat(xb,pooled) @ concat_k(Ws,Wn)^T + bn)
    mfma_gemm<256, 2><<<(N / 128) * 1, blk, 0, stream>>>(
        bufX, 256, Wcat, bn, hbuf, 128);

    // K5 + head fused (h2 lives in LDS only)
    k5_head<<<N / 64, blk, 0, stream>>>(hbuf, W1_b, b1, W2_b, b2, out);
}